// Round 1
// 103.660 us; speedup vs baseline: 1.0170x; 1.0170x over previous
//
#include <hip/hip_runtime.h>

// Problem dims (from reference setup_inputs)
#define BB 4
#define CC 64
#define HH 256
#define WW 256
#define NPIX (HH*WW)          // 65536
#define NCLS 4
#define NPAIR 12              // B*(NCLS-1)
#define HALF 512
#define MAXS 1024
#define NOUT (NPAIR*CC*MAXS)  // 786432
#define NBAND 64              // 4-row bands per image
#define BANDPIX (NPIX/NBAND)  // 1024

// ---------------------------------------------------------------------------
// Round 6: 2-kernel structure (was 3). The middle slot-assignment kernel is
// eliminated: K1 now ballot-compacts each band's class pixels into ORDERED
// per-(pair,band) hard/easy bucket lists (raster order preserved: rows ->
// waves -> lanes), and K3 maps slot->pixel itself via a per-pair band-count
// prefix (wave scan) + 6-step binary search + one L2-hot bucket read.
// Removes: K2 kernel (~2us), one launch gap (~1.5-2us), pd round-trip
// (256KB w+r), slots round-trip (48KB w+r), 2nd labels read (~3.8MB).
// The 2x ~41.3us 256MiB workspace poison-fills (81% HBM peak, rocprof top-5)
// are harness-fixed; this targets the ~23us controllable remainder.
// ---------------------------------------------------------------------------

// K1: fused argmax + separable 3x3 dilation + per-band bucket compaction.
// Block = one 4-row x 256-col band (256 blocks). Vertical 3-max in registers,
// horizontal 3-max via LDS (unchanged from measured-best r5 kernel).
// Then per row: 6 ballots (3 classes x hard/easy); lane0 of each wave stores
// the wave popcount into LDS; a 96-thread pass builds exclusive prefixes over
// (row, wave); each flagged pixel writes its in-image pixel index at its
// in-band rank. Per-band totals packed hard|easy<<16, one store per class.
// OOB halo rows use argmax=0 (safe: window always contains the center pixel).
__global__ void __launch_bounds__(256) k_count(
        const float* __restrict__ preds, const int* __restrict__ labels,
        int* __restrict__ hardBuf, int* __restrict__ easyBuf,
        unsigned* __restrict__ bandCounts) {
    __shared__ unsigned char vm[4][WW];
    __shared__ unsigned short cnt[96];   // [(cls,typ)=c2][ry][w] = c2*16+ry*4+w
    __shared__ unsigned short pre[96];   // exclusive prefix over (ry,w) per c2
    int bx = blockIdx.x;
    int b = bx >> 6, band = bx & 63;
    int y0 = band * 4;
    int x = threadIdx.x;
    const float* pb = preds + (size_t)b * NCLS * NPIX;

    unsigned char am[6];
#pragma unroll
    for (int r = 0; r < 6; ++r) {
        int y = y0 + r - 1;
        unsigned char a = 0;
        if (y >= 0 && y < HH) {
            const float* p = pb + y * WW + x;
            float best = p[0];
            int arg = 0;
#pragma unroll
            for (int c = 1; c < NCLS; ++c) {
                float v = p[(size_t)c * NPIX];
                if (v > best) { best = v; arg = c; }   // first-max wins (jnp.argmax)
            }
            a = (unsigned char)arg;
        }
        am[r] = a;
    }
    unsigned char vmr[4];
#pragma unroll
    for (int ry = 0; ry < 4; ++ry) {
        int m = am[ry];
        if (am[ry + 1] > m) m = am[ry + 1];
        if (am[ry + 2] > m) m = am[ry + 2];
        vmr[ry] = (unsigned char)m;
        vm[ry][x] = (unsigned char)m;
    }
    __syncthreads();

    int lane = x & 63, w = x >> 6;
    unsigned long long lt = (1ull << lane) - 1ull;   // lanemask_lt (lane<64 ok)

    int labv[4], pos[4], cls4[4], typ4[4];
#pragma unroll
    for (int ry = 0; ry < 4; ++ry) {
        int m = vmr[ry];
        if (x > 0)      { int v = vm[ry][x - 1]; if (v > m) m = v; }
        if (x < WW - 1) { int v = vm[ry][x + 1]; if (v > m) m = v; }
        int l = labels[b * NPIX + (y0 + ry) * WW + x];
        labv[ry] = l;
        cls4[ry] = l - 1;                 // -1 for ignore label 0
        typ4[ry] = (m == l) ? 1 : 0;      // 1 = easy, 0 = hard
        int p = 0;
#pragma unroll
        for (int c = 1; c <= 3; ++c) {
            unsigned long long hm = __ballot(l == c && m != c);
            unsigned long long em = __ballot(l == c && m == c);
            if (lane == 0) {
                cnt[((c - 1) * 2 + 0) * 16 + ry * 4 + w] = (unsigned short)__popcll(hm);
                cnt[((c - 1) * 2 + 1) * 16 + ry * 4 + w] = (unsigned short)__popcll(em);
            }
            if (l == c) p = (int)__popcll(((m != c) ? hm : em) & lt);
        }
        pos[ry] = p;
    }
    __syncthreads();

    if (x < 96) {                         // c2 = x>>4, k = x&15 over (ry,w)
        int base = x & ~15, k = x & 15;
        int s = 0;
        for (int j = 0; j < k; ++j) s += cnt[base + j];
        pre[x] = (unsigned short)s;
    }
    __syncthreads();

    if (x < 3) {                          // per-band totals, hard | easy<<16
        int th = pre[(x * 2 + 0) * 16 + 15] + cnt[(x * 2 + 0) * 16 + 15];
        int te = pre[(x * 2 + 1) * 16 + 15] + cnt[(x * 2 + 1) * 16 + 15];
        bandCounts[(b * 3 + x) * NBAND + band] = (unsigned)th | ((unsigned)te << 16);
    }
#pragma unroll
    for (int ry = 0; ry < 4; ++ry) {
        int cc = cls4[ry];
        if (cc >= 0) {
            int c2 = cc * 2 + typ4[ry];
            int r = pre[c2 * 16 + ry * 4 + w] + pos[ry];      // in-band rank
            int pair = b * 3 + cc;
            int* buf = typ4[ry] ? easyBuf : hardBuf;
            buf[(((pair << 6) | band) << 10) + r] = (y0 + ry) * WW + x;
        }
    }
}

// K3: gather. Block = one (pair, channel): 768 blocks, 4 slots/thread.
// Wave 0 scans the pair's 64 packed band counts into cumH/cumE (LDS); every
// thread then resolves its slots with the SAME hard/easy interval arithmetic
// as the previous passing kernel (hard rank r -> slot r; easy rank e ->
// slot 512+excess+e; invalid slots -> 0), finds the band by binary search,
// and reads the pixel index from the bucket (L2-hot: shared by all 64
// channel-blocks of the pair). Buckets need no init: off < band count always.
__global__ void __launch_bounds__(256) k_gather(
        const float* __restrict__ feat, const int* __restrict__ hardBuf,
        const int* __restrict__ easyBuf, const unsigned* __restrict__ bandCounts,
        float* __restrict__ out) {
    __shared__ int cumH[NBAND + 1], cumE[NBAND + 1];
    int blk = blockIdx.x;
    int pair = blk >> 6, c = blk & 63;
    int t = threadIdx.x;
    if (t < NBAND) {                       // wave 0: inclusive scan of 64 bands
        unsigned v = bandCounts[pair * NBAND + t];
        int hv = (int)(v & 0xffffu), ev = (int)(v >> 16);
#pragma unroll
        for (int off = 1; off < 64; off <<= 1) {
            int hu = __shfl_up(hv, off, 64);
            int eu = __shfl_up(ev, off, 64);
            if (t >= off) { hv += hu; ev += eu; }
        }
        cumH[t + 1] = hv;
        cumE[t + 1] = ev;
        if (t == 0) { cumH[0] = 0; cumE[0] = 0; }
    }
    __syncthreads();

    int Nh = cumH[NBAND], Ne = cumE[NBAND];
    int excess = Nh - HALF; if (excess < 0) excess = 0;
    int hardEnd = Nh < MAXS ? Nh : MAXS;
    int easyStart = HALF + excess;
    int easyEnd = easyStart + Ne; if (easyEnd > MAXS) easyEnd = MAXS;
    if (c == 0 && t == 0) out[NOUT + pair] = (float)(pair % 3 + 1);  // feat_label

    int b = pair / 3;
    const float* fp = feat + (size_t)(b * CC + c) * NPIX;
    float o[4];
#pragma unroll
    for (int j = 0; j < 4; ++j) {
        int s = t * 4 + j;
        bool isH = s < hardEnd;
        bool isE = (s >= easyStart) & (s < easyEnd);
        float val = 0.0f;
        if (isH | isE) {
            int r = isH ? s : s - easyStart;
            const int* cum = isH ? cumH : cumE;
            int lo = 0, hi = NBAND;        // invariant: cum[lo] <= r < cum[hi]
#pragma unroll
            for (int it = 0; it < 6; ++it) {
                int mid = (lo + hi) >> 1;
                if (cum[mid] <= r) lo = mid; else hi = mid;
            }
            int off = r - cum[lo];
            const int* buf = isH ? hardBuf : easyBuf;
            int pix = buf[(((pair << 6) | lo) << 10) + off];
            val = fp[pix];
        }
        o[j] = val;
    }
    ((float4*)out)[blk * 256 + t] = make_float4(o[0], o[1], o[2], o[3]);
}

extern "C" void kernel_launch(void* const* d_in, const int* in_sizes, int n_in,
                              void* d_out, int out_size, void* d_ws, size_t ws_size,
                              hipStream_t stream) {
    const float* feat   = (const float*)d_in[0];  // [B,C,H,W] fp32
    const int*   labels = (const int*)d_in[1];    // [B,H,W] int32
    const float* preds  = (const float*)d_in[2];  // [B,NCLS,H,W] fp32
    float* out = (float*)d_out;

    // workspace layout (16B-aligned): ordered pixel buckets + band counts.
    // Poison-safe: bucket entries beyond the written count are never read.
    int* hardBuf = (int*)d_ws;                                  // 12*64*1024 ints
    int* easyBuf = hardBuf + NPAIR * NBAND * 1024;              // 12*64*1024 ints
    unsigned* bandCounts = (unsigned*)(easyBuf + NPAIR * NBAND * 1024); // 768

    k_count<<<NBAND * BB, 256, 0, stream>>>(preds, labels, hardBuf, easyBuf, bandCounts);
    k_gather<<<NPAIR * CC, 256, 0, stream>>>(feat, hardBuf, easyBuf, bandCounts, out);
}

// Round 2
// 102.043 us; speedup vs baseline: 1.0331x; 1.0158x over previous
//
#include <hip/hip_runtime.h>

// Problem dims (from reference setup_inputs)
#define BB 4
#define CC 64
#define HH 256
#define WW 256
#define NPIX (HH*WW)          // 65536
#define NCLS 4
#define NPAIR 12              // B*(NCLS-1)
#define HALF 512
#define MAXS 1024
#define NOUT (NPAIR*CC*MAXS)  // 786432
#define NBAND 64              // 4-row bands per image
#define BANDPIX (NPIX/NBAND)  // 1024

// ---------------------------------------------------------------------------
// Round 7: same 2-kernel structure as r6 (103.7us), K1 untouched. K3 theory:
// latency-bound, not BW-bound -- each gathered float ends a ~1100-cycle
// dependent chain (6-dep-LDS binary search -> bucket read -> feat gather) and
// the 768-block grid gave only 12 waves/CU (38% occupancy) to hide it.
// Change: 3072 blocks, 1 slot/thread -> 8 resident blocks = 32 waves/CU
// (occupancy cap), ~2.7x in-flight gather parallelism. Slot arithmetic,
// search invariant, validity intervals identical to the passing kernel.
// The 2x ~41.5us 256MiB workspace poison-fills (81% HBM peak, rocprof top-5)
// are harness-fixed; controllable remainder is ~20.6us, mostly K3.
// ---------------------------------------------------------------------------

// K1: fused argmax + separable 3x3 dilation + per-band bucket compaction.
// Block = one 4-row x 256-col band (256 blocks). Vertical 3-max in registers,
// horizontal 3-max via LDS. Per row: 6 ballots (3 classes x hard/easy);
// per-wave popcounts -> LDS; 96-thread exclusive prefix over (row, wave);
// each flagged pixel writes its pixel index at its in-band rank (raster order
// preserved: rows -> waves -> lanes). Per-band totals packed hard|easy<<16.
// OOB halo rows use argmax=0 (safe: window always contains the center pixel).
__global__ void __launch_bounds__(256) k_count(
        const float* __restrict__ preds, const int* __restrict__ labels,
        int* __restrict__ hardBuf, int* __restrict__ easyBuf,
        unsigned* __restrict__ bandCounts) {
    __shared__ unsigned char vm[4][WW];
    __shared__ unsigned short cnt[96];   // [(cls,typ)=c2][ry][w] = c2*16+ry*4+w
    __shared__ unsigned short pre[96];   // exclusive prefix over (ry,w) per c2
    int bx = blockIdx.x;
    int b = bx >> 6, band = bx & 63;
    int y0 = band * 4;
    int x = threadIdx.x;
    const float* pb = preds + (size_t)b * NCLS * NPIX;

    unsigned char am[6];
#pragma unroll
    for (int r = 0; r < 6; ++r) {
        int y = y0 + r - 1;
        unsigned char a = 0;
        if (y >= 0 && y < HH) {
            const float* p = pb + y * WW + x;
            float best = p[0];
            int arg = 0;
#pragma unroll
            for (int c = 1; c < NCLS; ++c) {
                float v = p[(size_t)c * NPIX];
                if (v > best) { best = v; arg = c; }   // first-max wins (jnp.argmax)
            }
            a = (unsigned char)arg;
        }
        am[r] = a;
    }
    unsigned char vmr[4];
#pragma unroll
    for (int ry = 0; ry < 4; ++ry) {
        int m = am[ry];
        if (am[ry + 1] > m) m = am[ry + 1];
        if (am[ry + 2] > m) m = am[ry + 2];
        vmr[ry] = (unsigned char)m;
        vm[ry][x] = (unsigned char)m;
    }
    __syncthreads();

    int lane = x & 63, w = x >> 6;
    unsigned long long lt = (1ull << lane) - 1ull;   // lanemask_lt (lane<64 ok)

    int labv[4], pos[4], cls4[4], typ4[4];
#pragma unroll
    for (int ry = 0; ry < 4; ++ry) {
        int m = vmr[ry];
        if (x > 0)      { int v = vm[ry][x - 1]; if (v > m) m = v; }
        if (x < WW - 1) { int v = vm[ry][x + 1]; if (v > m) m = v; }
        int l = labels[b * NPIX + (y0 + ry) * WW + x];
        labv[ry] = l;
        cls4[ry] = l - 1;                 // -1 for ignore label 0
        typ4[ry] = (m == l) ? 1 : 0;      // 1 = easy, 0 = hard
        int p = 0;
#pragma unroll
        for (int c = 1; c <= 3; ++c) {
            unsigned long long hm = __ballot(l == c && m != c);
            unsigned long long em = __ballot(l == c && m == c);
            if (lane == 0) {
                cnt[((c - 1) * 2 + 0) * 16 + ry * 4 + w] = (unsigned short)__popcll(hm);
                cnt[((c - 1) * 2 + 1) * 16 + ry * 4 + w] = (unsigned short)__popcll(em);
            }
            if (l == c) p = (int)__popcll(((m != c) ? hm : em) & lt);
        }
        pos[ry] = p;
    }
    __syncthreads();

    if (x < 96) {                         // c2 = x>>4, k = x&15 over (ry,w)
        int base = x & ~15, k = x & 15;
        int s = 0;
        for (int j = 0; j < k; ++j) s += cnt[base + j];
        pre[x] = (unsigned short)s;
    }
    __syncthreads();

    if (x < 3) {                          // per-band totals, hard | easy<<16
        int th = pre[(x * 2 + 0) * 16 + 15] + cnt[(x * 2 + 0) * 16 + 15];
        int te = pre[(x * 2 + 1) * 16 + 15] + cnt[(x * 2 + 1) * 16 + 15];
        bandCounts[(b * 3 + x) * NBAND + band] = (unsigned)th | ((unsigned)te << 16);
    }
#pragma unroll
    for (int ry = 0; ry < 4; ++ry) {
        int cc = cls4[ry];
        if (cc >= 0) {
            int c2 = cc * 2 + typ4[ry];
            int r = pre[c2 * 16 + ry * 4 + w] + pos[ry];      // in-band rank
            int pair = b * 3 + cc;
            int* buf = typ4[ry] ? easyBuf : hardBuf;
            buf[(((pair << 6) | band) << 10) + r] = (y0 + ry) * WW + x;
        }
    }
}

// K3: gather. Block = one (pair, channel, slot-quarter): 3072 blocks,
// 1 slot/thread -> 8 resident blocks/CU = 32 waves/CU (occupancy cap) to
// hide the search->bucket->gather dependent chain. Wave 0 scans the pair's
// 64 packed band counts into cumH/cumE (LDS); each thread resolves its slot
// with the SAME interval arithmetic as the passing kernel (hard rank r ->
// slot r; easy rank e -> slot 512+excess+e; invalid slots -> 0), finds the
// band by 6-step binary search, reads the pixel index from the bucket
// (L2-hot: shared by all 256 blocks of the pair), gathers, stores coalesced.
// Buckets need no init: off < per-band count always.
__global__ void __launch_bounds__(256) k_gather(
        const float* __restrict__ feat, const int* __restrict__ hardBuf,
        const int* __restrict__ easyBuf, const unsigned* __restrict__ bandCounts,
        float* __restrict__ out) {
    __shared__ int cumH[NBAND + 1], cumE[NBAND + 1];
    int blk = blockIdx.x;
    int pc = blk >> 2;                     // pair*CC + c
    int q = blk & 3;                       // slot quarter
    int pair = pc >> 6, c = pc & 63;
    int t = threadIdx.x;
    if (t < NBAND) {                       // wave 0: inclusive scan of 64 bands
        unsigned v = bandCounts[pair * NBAND + t];
        int hv = (int)(v & 0xffffu), ev = (int)(v >> 16);
#pragma unroll
        for (int off = 1; off < 64; off <<= 1) {
            int hu = __shfl_up(hv, off, 64);
            int eu = __shfl_up(ev, off, 64);
            if (t >= off) { hv += hu; ev += eu; }
        }
        cumH[t + 1] = hv;
        cumE[t + 1] = ev;
        if (t == 0) { cumH[0] = 0; cumE[0] = 0; }
    }
    __syncthreads();

    int Nh = cumH[NBAND], Ne = cumE[NBAND];
    int excess = Nh - HALF; if (excess < 0) excess = 0;
    int hardEnd = Nh < MAXS ? Nh : MAXS;
    int easyStart = HALF + excess;
    int easyEnd = easyStart + Ne; if (easyEnd > MAXS) easyEnd = MAXS;
    if (c == 0 && q == 0 && t == 0)
        out[NOUT + pair] = (float)(pair % 3 + 1);            // feat_label

    int b = pair / 3;
    const float* fp = feat + (size_t)(b * CC + c) * NPIX;
    int s = q * 256 + t;
    bool isH = s < hardEnd;
    bool isE = (s >= easyStart) & (s < easyEnd);
    float val = 0.0f;
    if (isH | isE) {
        int r = isH ? s : s - easyStart;
        const int* cum = isH ? cumH : cumE;
        int lo = 0, hi = NBAND;            // invariant: cum[lo] <= r < cum[hi]
#pragma unroll
        for (int it = 0; it < 6; ++it) {
            int mid = (lo + hi) >> 1;
            if (cum[mid] <= r) lo = mid; else hi = mid;
        }
        int off = r - cum[lo];
        const int* buf = isH ? hardBuf : easyBuf;
        int pix = buf[(((pair << 6) | lo) << 10) + off];
        val = fp[pix];
    }
    out[blk * 256 + t] = val;              // coalesced: consecutive t -> dwords
}

extern "C" void kernel_launch(void* const* d_in, const int* in_sizes, int n_in,
                              void* d_out, int out_size, void* d_ws, size_t ws_size,
                              hipStream_t stream) {
    const float* feat   = (const float*)d_in[0];  // [B,C,H,W] fp32
    const int*   labels = (const int*)d_in[1];    // [B,H,W] int32
    const float* preds  = (const float*)d_in[2];  // [B,NCLS,H,W] fp32
    float* out = (float*)d_out;

    // workspace layout (16B-aligned): ordered pixel buckets + band counts.
    // Poison-safe: bucket entries beyond the written count are never read.
    int* hardBuf = (int*)d_ws;                                  // 12*64*1024 ints
    int* easyBuf = hardBuf + NPAIR * NBAND * 1024;              // 12*64*1024 ints
    unsigned* bandCounts = (unsigned*)(easyBuf + NPAIR * NBAND * 1024); // 768

    k_count<<<NBAND * BB, 256, 0, stream>>>(preds, labels, hardBuf, easyBuf, bandCounts);
    k_gather<<<NPAIR * CC * 4, 256, 0, stream>>>(feat, hardBuf, easyBuf, bandCounts, out);
}